// Round 2
// baseline (683.039 us; speedup 1.0000x reference)
//
#include <hip/hip_runtime.h>
#include <hip/hip_bf16.h>

#define N_NODE 50000
#define N_USED 50000
#define N_EDGE 800000
#define N_REL  8
#define NB     32          // nodes per block tile
#define NTHREADS 512
#define NWAVE  8
#define PADF   132         // fp32 agg row stride (floats): 528 B, 16B-aligned
#define PADB   136         // bf16 agg row stride (bf16):   272 B, 16B-aligned

typedef __bf16 bf16x8 __attribute__((ext_vector_type(8)));
typedef float  f32x4  __attribute__((ext_vector_type(4)));

__device__ __forceinline__ float us_to_f(unsigned short u) {
    union { unsigned i; float f; } v; v.i = ((unsigned)u) << 16; return v.f;
}
__device__ __forceinline__ unsigned pack2(float a, float b) {
    __hip_bfloat16 ha = __float2bfloat16(a), hb = __float2bfloat16(b);
    unsigned short ua = *reinterpret_cast<unsigned short*>(&ha);
    unsigned short ub = *reinterpret_cast<unsigned short*>(&hb);
    return (unsigned)ua | ((unsigned)ub << 16);
}

// ---- x (fp32, [N_USED][128]) -> xb (bf16) ----
__global__ __launch_bounds__(256) void k_cvt_x(const float* __restrict__ x,
                                               __hip_bfloat16* __restrict__ xb) {
    int i = blockIdx.x * 256 + threadIdx.x;
    float4 v = reinterpret_cast<const float4*>(x)[i];
    __hip_bfloat16 h0 = __float2bfloat16(v.x);
    __hip_bfloat16 h1 = __float2bfloat16(v.y);
    __hip_bfloat16 h2 = __float2bfloat16(v.z);
    __hip_bfloat16 h3 = __float2bfloat16(v.w);
    ushort4 o;
    o.x = *reinterpret_cast<unsigned short*>(&h0);
    o.y = *reinterpret_cast<unsigned short*>(&h1);
    o.z = *reinterpret_cast<unsigned short*>(&h2);
    o.w = *reinterpret_cast<unsigned short*>(&h3);
    reinterpret_cast<ushort4*>(xb)[i] = o;
}

// ---- W [r][c][h] fp32 -> Wt [r][h][c] bf16 ----
__global__ __launch_bounds__(256) void k_cvt_w(const float* __restrict__ w,
                                               __hip_bfloat16* __restrict__ wt) {
    int i = blockIdx.x * 256 + threadIdx.x;       // 131072 elems
    int r = i >> 14, c = (i >> 7) & 127, h = i & 127;
    wt[(((size_t)r << 7) + h) * 128 + c] = __float2bfloat16(w[i]);
}

// ---- fused: per-tile CSR aggregation (LDS) + MFMA with W ----
__global__ __launch_bounds__(NTHREADS, 1)
void k_fused(const __hip_bfloat16* __restrict__ xb,
             const __hip_bfloat16* __restrict__ wt,
             const int* __restrict__ ptr,
             const int* __restrict__ idx,
             const int* __restrict__ rel,
             float* __restrict__ out)
{
    __shared__ float aggf[N_REL * NB * PADF];     // 135168 B
    __shared__ int ptr_s[NB + 1];

    const int tid  = threadIdx.x;
    const int lane = tid & 63;
    const int w    = tid >> 6;
    const int t0   = blockIdx.x * NB;
    const int nn   = min(NB, N_NODE - t0);

    // zero agg
    const f32x4 z4 = {0.f, 0.f, 0.f, 0.f};
    for (int i = tid * 4; i < N_REL * NB * PADF; i += NTHREADS * 4)
        *reinterpret_cast<f32x4*>(&aggf[i]) = z4;
    if (tid <= nn) ptr_s[tid] = ptr[t0 + tid];
    __syncthreads();

    // ---- phase 1: edge-parallel aggregation ----
    const int e_lo = ptr_s[0];
    const int e_hi = ptr_s[nn];
    const int bnd  = (lane < nn) ? ptr_s[lane + 1] : 0x7fffffff;
    const int nedge = e_hi - e_lo;
    const int chunk = (nedge + NWAVE - 1) / NWAVE;
    int e0 = e_lo + w * chunk;
    int e1 = min(e0 + chunk, e_hi);

    const unsigned short* xs = (const unsigned short*)xb;

    for (int e = e0; e < e1; e += 8) {
        int ii[8], rr[8];
#pragma unroll
        for (int b = 0; b < 8; ++b) {
            int ee = min(e + b, e1 - 1);
            ii[b] = idx[ee];
            rr[b] = rel[ee];
        }
        unsigned short ul[8], uh[8];
#pragma unroll
        for (int b = 0; b < 8; ++b) {
            const unsigned short* xr = xs + (size_t)ii[b] * 128;
            ul[b] = xr[lane];
            uh[b] = xr[64 + lane];
        }
#pragma unroll
        for (int b = 0; b < 8; ++b) {
            if (e + b < e1) {
                int node = (int)__popcll(__ballot(bnd <= e + b));
                float* p = &aggf[(rr[b] * NB + node) * PADF];
                unsafeAtomicAdd(p + lane,      us_to_f(ul[b]));
                unsafeAtomicAdd(p + 64 + lane, us_to_f(uh[b]));
            }
        }
    }
    __syncthreads();

    // ---- phase 2: in-place repack agg fp32 -> bf16 ----
    {
        const int row = tid >> 1;                 // 0..255  (= rel*NB + node)
        const int c0  = (tid & 1) * 64;
        f32x4 tmp[16];
        const f32x4* src = reinterpret_cast<const f32x4*>(&aggf[row * PADF + c0]);
#pragma unroll
        for (int i = 0; i < 16; ++i) tmp[i] = src[i];
        __syncthreads();
        unsigned* dst = reinterpret_cast<unsigned*>(aggf) + row * (PADB / 2) + c0 / 2;
#pragma unroll
        for (int i = 0; i < 16; ++i) {
            dst[i * 2]     = pack2(tmp[i][0], tmp[i][1]);
            dst[i * 2 + 1] = pack2(tmp[i][2], tmp[i][3]);
        }
    }
    __syncthreads();

    // ---- phase 3: out[32 nodes][128] += agg[32][1024] @ Wstack[1024][128] ----
    // 8 waves partition N=128 into 16-wide slices; each wave does M=32 (rc=2), K=1024.
    const __hip_bfloat16* aggb = (const __hip_bfloat16*)aggf;
    const int rlo = lane & 15, khi = lane >> 4;
    f32x4 acc0 = {0.f, 0.f, 0.f, 0.f}, acc1 = {0.f, 0.f, 0.f, 0.f};
#pragma unroll 4
    for (int kc = 0; kc < 32; ++kc) {
        const int r  = kc >> 2;
        const int c0 = (kc & 3) * 32 + khi * 8;
        bf16x8 bfrag = *reinterpret_cast<const bf16x8*>(
            &wt[(size_t)(((r << 7) + (w << 4) + rlo) << 7) + c0]);
        bf16x8 a0 = *reinterpret_cast<const bf16x8*>(&aggb[(r * NB + rlo) * PADB + c0]);
        bf16x8 a1 = *reinterpret_cast<const bf16x8*>(&aggb[(r * NB + 16 + rlo) * PADB + c0]);
        acc0 = __builtin_amdgcn_mfma_f32_16x16x32_bf16(a0, bfrag, acc0, 0, 0, 0);
        acc1 = __builtin_amdgcn_mfma_f32_16x16x32_bf16(a1, bfrag, acc1, 0, 0, 0);
    }
    // C/D: col = lane&15 (h), row = (lane>>4)*4 + j (node)
#pragma unroll
    for (int j = 0; j < 4; ++j) {
        int n0 = t0 + (khi << 2) + j;
        if (n0 < N_NODE) out[(size_t)n0 * 128 + (w << 4) + rlo] = acc0[j];
        int n1 = n0 + 16;
        if (n1 < N_NODE) out[(size_t)n1 * 128 + (w << 4) + rlo] = acc1[j];
    }
}

// ---- fallback (tiny workspace): direct fp32 compute, slow but correct ----
__global__ __launch_bounds__(256) void k_direct(const float* __restrict__ x,
                                                const float* __restrict__ w,
                                                const int* __restrict__ ptr,
                                                const int* __restrict__ idx,
                                                const int* __restrict__ rel,
                                                float* __restrict__ out) {
    const int lane = threadIdx.x & 63;
    const int s = blockIdx.x * 4 + (threadIdx.x >> 6);
    if (s >= N_NODE) return;
    const int e0 = ptr[s], e1 = ptr[s + 1];
    const int h = lane * 2;
    float ax = 0.f, ay = 0.f;
    for (int e = e0; e < e1; ++e) {
        const float* xr = x + (size_t)idx[e] * 128;
        const float* wr = w + (size_t)rel[e] * 16384 + h;
        for (int c = 0; c < 128; ++c) {
            float xv = xr[c];
            ax += xv * wr[(size_t)c * 128];
            ay += xv * wr[(size_t)c * 128 + 1];
        }
    }
    float2 o = {ax, ay};
    reinterpret_cast<float2*>(out + (size_t)s * 128)[lane] = o;
}

extern "C" void kernel_launch(void* const* d_in, const int* in_sizes, int n_in,
                              void* d_out, int out_size, void* d_ws, size_t ws_size,
                              hipStream_t stream) {
    const float* x   = (const float*)d_in[0];
    const float* w   = (const float*)d_in[1];
    const int*   ptr = (const int*)d_in[2];
    const int*   idx = (const int*)d_in[3];
    const int*   rel = (const int*)d_in[4];
    float*       out = (float*)d_out;

    const size_t off_xb = 0;                       // 12,800,000 B
    const size_t off_wt = 12800000;                //    262,144 B
    const size_t need   = off_wt + (size_t)N_REL * 128 * 128 * 2;

    if (ws_size >= need) {
        __hip_bfloat16* xb = (__hip_bfloat16*)((char*)d_ws + off_xb);
        __hip_bfloat16* wt = (__hip_bfloat16*)((char*)d_ws + off_wt);
        k_cvt_x<<<6250, 256, 0, stream>>>(x, xb);
        k_cvt_w<<<512, 256, 0, stream>>>(w, wt);
        k_fused<<<(N_NODE + NB - 1) / NB, NTHREADS, 0, stream>>>(xb, wt, ptr, idx, rel, out);
    } else {
        k_direct<<<12500, 256, 0, stream>>>(x, w, ptr, idx, rel, out);
    }
}

// Round 3
// 217.624 us; speedup vs baseline: 3.1386x; 3.1386x over previous
//
#include <hip/hip_runtime.h>
#include <hip/hip_bf16.h>

#define N_NODE 50000
#define N_USED 50000
#define N_EDGE 800000
#define N_REL  8
#define NB     16          // nodes per block
#define NTHREADS 512
#define PADU   68          // uint stride of one (rel,node) channel row

typedef __bf16 bf16x8 __attribute__((ext_vector_type(8)));
typedef float  f32x4  __attribute__((ext_vector_type(4)));

__device__ __forceinline__ float bf_lo(unsigned u) {
    union { unsigned i; float f; } v; v.i = u << 16; return v.f;
}
__device__ __forceinline__ float bf_hi(unsigned u) {
    union { unsigned i; float f; } v; v.i = u & 0xffff0000u; return v.f;
}
__device__ __forceinline__ unsigned pack2(float a, float b) {
    __hip_bfloat16 ha = __float2bfloat16(a), hb = __float2bfloat16(b);
    unsigned short ua = *reinterpret_cast<unsigned short*>(&ha);
    unsigned short ub = *reinterpret_cast<unsigned short*>(&hb);
    return (unsigned)ua | ((unsigned)ub << 16);
}

// ---- x (fp32, [N_USED][128]) -> xb (bf16) ----
__global__ __launch_bounds__(256) void k_cvt_x(const float* __restrict__ x,
                                               __hip_bfloat16* __restrict__ xb) {
    int i = blockIdx.x * 256 + threadIdx.x;
    float4 v = reinterpret_cast<const float4*>(x)[i];
    __hip_bfloat16 h0 = __float2bfloat16(v.x);
    __hip_bfloat16 h1 = __float2bfloat16(v.y);
    __hip_bfloat16 h2 = __float2bfloat16(v.z);
    __hip_bfloat16 h3 = __float2bfloat16(v.w);
    ushort4 o;
    o.x = *reinterpret_cast<unsigned short*>(&h0);
    o.y = *reinterpret_cast<unsigned short*>(&h1);
    o.z = *reinterpret_cast<unsigned short*>(&h2);
    o.w = *reinterpret_cast<unsigned short*>(&h3);
    reinterpret_cast<ushort4*>(xb)[i] = o;
}

// ---- W [r][c][h] fp32 -> Wt [r][h][c] bf16 ----
__global__ __launch_bounds__(256) void k_cvt_w(const float* __restrict__ w,
                                               __hip_bfloat16* __restrict__ wt) {
    int i = blockIdx.x * 256 + threadIdx.x;       // 131072 elems
    int r = i >> 14, c = (i >> 7) & 127, h = i & 127;
    wt[(((size_t)r << 7) + h) * 128 + c] = __float2bfloat16(w[i]);
}

// ---- fused: wave-per-node register aggregation + MFMA ----
__global__ __launch_bounds__(NTHREADS, 4)
void k_fused(const __hip_bfloat16* __restrict__ xb,
             const __hip_bfloat16* __restrict__ wt,
             const int* __restrict__ ptr,
             const int* __restrict__ idx,
             const int* __restrict__ rel,
             float* __restrict__ out)
{
    __shared__ unsigned agg[N_REL][NB][PADU];     // 34816 B -> 4 blocks/CU

    const int tid  = threadIdx.x;
    const int lane = tid & 63;
    const int w    = tid >> 6;
    const int t0   = blockIdx.x * NB;             // 3125*16 = 50000 exact
    const unsigned* xu = (const unsigned*)xb;     // lane owns ch {2*lane, 2*lane+1}

    // ---- phase 1: each wave aggregates 2 nodes in registers ----
#pragma unroll
    for (int half = 0; half < 2; ++half) {
        const int n  = w * 2 + half;
        const int e0 = ptr[t0 + n];
        const int e1 = ptr[t0 + n + 1];
        float al[N_REL], ah[N_REL];
#pragma unroll
        for (int r = 0; r < N_REL; ++r) { al[r] = 0.f; ah[r] = 0.f; }

        for (int e = e0; e < e1; e += 8) {
            const int m = e1 - e;                 // >= 1
            int ib[8], rb[8];
#pragma unroll
            for (int b = 0; b < 8; ++b) {
                int ee = (b < m) ? e + b : e;     // clamped dup; masked below
                ib[b] = idx[ee];
                rb[b] = rel[ee];
            }
            unsigned ub[8];
#pragma unroll
            for (int b = 0; b < 8; ++b)
                ub[b] = xu[(size_t)ib[b] * 64 + lane];
#pragma unroll
            for (int b = 0; b < 8; ++b) {
                if (b < m) {
                    float lo = bf_lo(ub[b]), hi = bf_hi(ub[b]);
                    switch (__builtin_amdgcn_readfirstlane(rb[b])) {
                        case 0: al[0] += lo; ah[0] += hi; break;
                        case 1: al[1] += lo; ah[1] += hi; break;
                        case 2: al[2] += lo; ah[2] += hi; break;
                        case 3: al[3] += lo; ah[3] += hi; break;
                        case 4: al[4] += lo; ah[4] += hi; break;
                        case 5: al[5] += lo; ah[5] += hi; break;
                        case 6: al[6] += lo; ah[6] += hi; break;
                        case 7: al[7] += lo; ah[7] += hi; break;
                    }
                }
            }
        }
#pragma unroll
        for (int r = 0; r < N_REL; ++r)
            agg[r][n][lane] = pack2(al[r], ah[r]);
    }
    __syncthreads();

    // ---- phase 2: out[16 nodes][128] = agg[16][K=1024] @ Wstack[1024][128] ----
    // wave w owns h-slice [w*16, w*16+16); full M=16, K = 8 rels * 128 ch
    const int rlo = lane & 15, khi = lane >> 4;
    const int h   = (w << 4) + rlo;
    f32x4 acc = {0.f, 0.f, 0.f, 0.f};
#pragma unroll 8
    for (int kc = 0; kc < 32; ++kc) {
        const int r  = kc >> 2;
        const int cu = (kc & 3) * 16 + (khi << 2);    // uint offset (=ch/2)
        bf16x8 afrag = *reinterpret_cast<const bf16x8*>(&agg[r][rlo][cu]);
        bf16x8 bfrag = *reinterpret_cast<const bf16x8*>(
            &wt[(size_t)(((r << 7) + h) << 7) + (kc & 3) * 32 + (khi << 3)]);
        acc = __builtin_amdgcn_mfma_f32_16x16x32_bf16(afrag, bfrag, acc, 0, 0, 0);
    }
    // C/D: col = lane&15 (h), row = (lane>>4)*4 + j (node)
#pragma unroll
    for (int j = 0; j < 4; ++j) {
        int n = t0 + (khi << 2) + j;
        out[(size_t)n * 128 + h] = acc[j];
    }
}

// ---- fallback (tiny workspace): direct fp32 compute, slow but correct ----
__global__ __launch_bounds__(256) void k_direct(const float* __restrict__ x,
                                                const float* __restrict__ w,
                                                const int* __restrict__ ptr,
                                                const int* __restrict__ idx,
                                                const int* __restrict__ rel,
                                                float* __restrict__ out) {
    const int lane = threadIdx.x & 63;
    const int s = blockIdx.x * 4 + (threadIdx.x >> 6);
    if (s >= N_NODE) return;
    const int e0 = ptr[s], e1 = ptr[s + 1];
    const int h = lane * 2;
    float ax = 0.f, ay = 0.f;
    for (int e = e0; e < e1; ++e) {
        const float* xr = x + (size_t)idx[e] * 128;
        const float* wr = w + (size_t)rel[e] * 16384 + h;
        for (int c = 0; c < 128; ++c) {
            float xv = xr[c];
            ax += xv * wr[(size_t)c * 128];
            ay += xv * wr[(size_t)c * 128 + 1];
        }
    }
    float2 o = {ax, ay};
    reinterpret_cast<float2*>(out + (size_t)s * 128)[lane] = o;
}

extern "C" void kernel_launch(void* const* d_in, const int* in_sizes, int n_in,
                              void* d_out, int out_size, void* d_ws, size_t ws_size,
                              hipStream_t stream) {
    const float* x   = (const float*)d_in[0];
    const float* w   = (const float*)d_in[1];
    const int*   ptr = (const int*)d_in[2];
    const int*   idx = (const int*)d_in[3];
    const int*   rel = (const int*)d_in[4];
    float*       out = (float*)d_out;

    const size_t off_xb = 0;                        // 12,800,000 B
    const size_t off_wt = 12800000;                 //    262,144 B
    const size_t need   = off_wt + (size_t)N_REL * 128 * 128 * 2;

    if (ws_size >= need) {
        __hip_bfloat16* xb = (__hip_bfloat16*)((char*)d_ws + off_xb);
        __hip_bfloat16* wt = (__hip_bfloat16*)((char*)d_ws + off_wt);
        k_cvt_x<<<6250, 256, 0, stream>>>(x, xb);
        k_cvt_w<<<512, 256, 0, stream>>>(w, wt);
        k_fused<<<N_NODE / NB, NTHREADS, 0, stream>>>(xb, wt, ptr, idx, rel, out);
    } else {
        k_direct<<<12500, 256, 0, stream>>>(x, w, ptr, idx, rel, out);
    }
}